// Round 1
// baseline (718.772 us; speedup 1.0000x reference)
//
#include <hip/hip_runtime.h>
#include <hip/hip_bf16.h>
#include <stdint.h>
#include <math.h>

#define DEV __device__ __forceinline__

using bf16 = __hip_bfloat16;
typedef __attribute__((ext_vector_type(8))) short bf16x8;
typedef __attribute__((ext_vector_type(4))) float f32x4;

static constexpr int NB  = 8;
static constexpr int NSW = 512;
static constexpr int NSE = 128;
static constexpr int ND  = 1024;
static constexpr int NH  = 16;
static constexpr int NFF = 4096;
static constexpr int NS  = NSW + NSE;   // 640
static constexpr int NHD = 64;

DEV f32x4 mfma16(bf16x8 a, bf16x8 b, f32x4 c){
  return __builtin_amdgcn_mfma_f32_16x16x32_bf16(a, b, c, 0, 0, 0);
}

DEV void gload16(const bf16* g, bf16* l){
  __builtin_amdgcn_global_load_lds((const __attribute__((address_space(1))) void*)g,
                                   (__attribute__((address_space(3))) void*)l,
                                   16, 0, 0);
}

DEV bf16 tobf(float f){ return __float2bfloat16(f); }

union PK4 { bf16 h[4]; short4 s; };

// ---------- casts: fp32 -> bf16, plus build concatenated hidden ----------
__global__ __launch_bounds__(256) void cast_word_k(const float* __restrict__ wh,
                                                   bf16* __restrict__ whb,
                                                   bf16* __restrict__ hid){
  long i = ((long)blockIdx.x*256 + threadIdx.x)*4;
  float4 v = *reinterpret_cast<const float4*>(wh + i);
  PK4 p; p.h[0]=tobf(v.x); p.h[1]=tobf(v.y); p.h[2]=tobf(v.z); p.h[3]=tobf(v.w);
  *reinterpret_cast<short4*>(whb + i) = p.s;
  long row = i >> 10; int c = (int)(i & 1023);
  int b = (int)(row >> 9), s = (int)(row & 511);
  *reinterpret_cast<short4*>(hid + ((long)(b*NS + s) << 10) + c) = p.s;
}

__global__ __launch_bounds__(256) void cast_ent_k(const float* __restrict__ eh,
                                                  bf16* __restrict__ ehb,
                                                  bf16* __restrict__ hid){
  long i = ((long)blockIdx.x*256 + threadIdx.x)*4;
  float4 v = *reinterpret_cast<const float4*>(eh + i);
  PK4 p; p.h[0]=tobf(v.x); p.h[1]=tobf(v.y); p.h[2]=tobf(v.z); p.h[3]=tobf(v.w);
  *reinterpret_cast<short4*>(ehb + i) = p.s;
  long row = i >> 10; int c = (int)(i & 1023);
  int b = (int)(row >> 7), s = (int)(row & 127);
  *reinterpret_cast<short4*>(hid + ((long)(b*NS + NSW + s) << 10) + c) = p.s;
}

// ---------- weight transpose+cast: in (R,C) fp32 -> out (C,R) bf16 ----------
__global__ void transpose_cast_k(const float* __restrict__ in, bf16* __restrict__ out,
                                 int R, int C){
  __shared__ float tile[32][33];
  const int c0 = blockIdx.x*32, r0 = blockIdx.y*32;
  const int tx = threadIdx.x, ty = threadIdx.y;
  #pragma unroll
  for (int i=0;i<4;i++)
    tile[ty + i*8][tx] = in[(long)(r0 + ty + i*8)*C + c0 + tx];
  __syncthreads();
  #pragma unroll
  for (int i=0;i<4;i++){
    int rr = ty + i*8;
    out[(long)(c0 + rr)*R + r0 + tx] = tobf(tile[tx][rr]);
  }
}

// ---------- GEMM: C(M,N) = A(M,K) @ Bt(N,K)^T + bias, bf16 MFMA ----------
// EPI: 0 = bf16 out (M,N); 1 = V scatter -> Vt(B,H,64,640) bf16;
//      2 = fp32 out (M,N); 3 = GELU(exact) -> bf16 out (M,N)
template<int EPI>
__global__ __launch_bounds__(256) void gemm_bt_k(const bf16* __restrict__ A,
                                                 const bf16* __restrict__ Bt,
                                                 const float* __restrict__ bias,
                                                 void* __restrict__ Cout,
                                                 int M, int N, int K){
  __shared__ __align__(16) bf16 As[128*64];
  __shared__ __align__(16) bf16 Bs[128*64];
  const int tid = threadIdx.x;
  const int m0 = blockIdx.y*128, n0 = blockIdx.x*128;
  const int wid = tid>>6, lane = tid&63;
  const int wr = wid>>1, wc = wid&1;
  const int lr = lane&15, lg = lane>>4;

  const f32x4 zero = {0.f,0.f,0.f,0.f};
  f32x4 acc[4][4];
  #pragma unroll
  for (int m=0;m<4;m++)
    #pragma unroll
    for (int n=0;n<4;n++) acc[m][n] = zero;

  for (int kt=0; kt<K; kt+=64){
    #pragma unroll
    for (int i=0;i<4;i++){
      int idx = i*256 + tid;
      int row = idx>>3, kc = idx&7;
      gload16(A + (long)(m0+row)*K + kt + kc*8, As + idx*8);
    }
    #pragma unroll
    for (int i=0;i<4;i++){
      int idx = i*256 + tid;
      int row = idx>>3, kc = idx&7;
      gload16(Bt + (long)(n0+row)*K + kt + kc*8, Bs + idx*8);
    }
    __syncthreads();
    #pragma unroll
    for (int ks=0; ks<2; ks++){
      bf16x8 af[4], bg[4];
      #pragma unroll
      for (int m=0;m<4;m++)
        af[m] = *reinterpret_cast<const bf16x8*>(As + (wr*64 + m*16 + lr)*64 + ks*32 + lg*8);
      #pragma unroll
      for (int n=0;n<4;n++)
        bg[n] = *reinterpret_cast<const bf16x8*>(Bs + (wc*64 + n*16 + lr)*64 + ks*32 + lg*8);
      #pragma unroll
      for (int m=0;m<4;m++)
        #pragma unroll
        for (int n=0;n<4;n++)
          acc[m][n] = mfma16(af[m], bg[n], acc[m][n]);
    }
    __syncthreads();
  }

  #pragma unroll
  for (int m=0;m<4;m++){
    const int rbase = m0 + wr*64 + m*16 + lg*4;
    #pragma unroll
    for (int n=0;n<4;n++){
      const int col = n0 + wc*64 + n*16 + lr;
      const float bsv = bias[col];
      #pragma unroll
      for (int r=0;r<4;r++){
        const int rw = rbase + r;
        float v = acc[m][n][r] + bsv;
        if constexpr (EPI == 0){
          ((bf16*)Cout)[(long)rw*N + col] = tobf(v);
        } else if constexpr (EPI == 1){
          int bb = rw / NS, ss = rw % NS, hh = col >> 6, dd = col & 63;
          ((bf16*)Cout)[((long)((bb*NH + hh)*NHD + dd))*NS + ss] = tobf(v);
        } else if constexpr (EPI == 2){
          ((float*)Cout)[(long)rw*N + col] = v;
        } else {
          float ge = 0.5f*v*(1.0f + erff(v*0.70710678118654752f));
          ((bf16*)Cout)[(long)rw*N + col] = tobf(ge);
        }
      }
    }
  }
}

// ---------- fused entity-aware flash attention ----------
// One wave handles 16 queries of one (b,h); online softmax over 20 tiles of 32 keys.
__global__ __launch_bounds__(256) void attn_k(
    const bf16* __restrict__ Qw2w, const bf16* __restrict__ Qw2e,
    const bf16* __restrict__ Qe2w, const bf16* __restrict__ Qe2e,
    const bf16* __restrict__ Kb,   const bf16* __restrict__ Vt,
    const float* __restrict__ wm,  const float* __restrict__ em,
    bf16* __restrict__ ctx){
  __shared__ __align__(16) bf16 Plds[4][16*40];   // per-wave P tile, row stride 40
  const int tid = threadIdx.x, wid = tid>>6, lane = tid&63;
  const int lr = lane&15, lg = lane>>4;
  const int w   = blockIdx.x*4 + wid;
  const int b   = w / (NH*(NS/16));
  const int rem = w % (NH*(NS/16));
  const int h   = rem / (NS/16);
  const int qt  = rem % (NS/16);
  const int q0  = qt*16;

  const bf16 *Qa, *Qb; long qrow;
  if (q0 < NSW){ Qa = Qw2w; Qb = Qw2e; qrow = (long)b*NSW + q0; }
  else         { Qa = Qe2w; Qb = Qe2e; qrow = (long)b*NSE + (q0 - NSW); }

  bf16x8 qa[2], qb[2];
  #pragma unroll
  for (int dc=0; dc<2; dc++){
    long o = (qrow + lr)*ND + h*NHD + dc*32 + lg*8;
    qa[dc] = *reinterpret_cast<const bf16x8*>(Qa + o);
    qb[dc] = *reinterpret_cast<const bf16x8*>(Qb + o);
  }

  const f32x4 zero = {0.f,0.f,0.f,0.f};
  f32x4 cacc[4];
  #pragma unroll
  for (int dt=0;dt<4;dt++) cacc[dt]=zero;
  float mrow[4], lsum[4];
  #pragma unroll
  for (int r=0;r<4;r++){ mrow[r]=-1e30f; lsum[r]=0.f; }

  const bf16* Kbase = Kb + (long)b*NS*ND + h*NHD;
  const bf16* Vbase = Vt + (long)((b*NH + h)*NHD)*NS;
  bf16* pw = &Plds[wid][0];

  for (int kt=0; kt<NS/32; kt++){
    const int k0 = kt*32;
    const bool word = (k0 < NSW);
    const bf16x8* qf = word ? qa : qb;

    f32x4 sc[2]; sc[0]=zero; sc[1]=zero;
    #pragma unroll
    for (int sub=0; sub<2; sub++)
      #pragma unroll
      for (int dc=0; dc<2; dc++){
        bf16x8 kf = *reinterpret_cast<const bf16x8*>(
            Kbase + (long)(k0 + sub*16 + lr)*ND + dc*32 + lg*8);
        sc[sub] = mfma16(qf[dc], kf, sc[sub]);
      }

    float msk[2];
    #pragma unroll
    for (int sub=0; sub<2; sub++){
      int k = k0 + sub*16 + lr;
      msk[sub] = word ? wm[b*NSW + k] : em[b*NSE + (k - NSW)];
    }

    float p0v[4], p1v[4], alpha[4];
    #pragma unroll
    for (int r=0;r<4;r++){
      float s0 = sc[0][r]*0.125f + msk[0];
      float s1 = sc[1][r]*0.125f + msk[1];
      float t = fmaxf(s0, s1);
      #pragma unroll
      for (int o=8;o;o>>=1) t = fmaxf(t, __shfl_xor(t, o, 16));
      float mn = fmaxf(mrow[r], t);
      alpha[r] = __expf(mrow[r] - mn);
      mrow[r] = mn;
      float p0 = __expf(s0 - mn), p1 = __expf(s1 - mn);
      float ps = p0 + p1;
      #pragma unroll
      for (int o=8;o;o>>=1) ps += __shfl_xor(ps, o, 16);
      lsum[r] = lsum[r]*alpha[r] + ps;
      p0v[r]=p0; p1v[r]=p1;
    }
    #pragma unroll
    for (int dt=0;dt<4;dt++)
      #pragma unroll
      for (int r=0;r<4;r++) cacc[dt][r] *= alpha[r];

    #pragma unroll
    for (int r=0;r<4;r++){
      pw[(lg*4+r)*40 + lr]      = tobf(p0v[r]);
      pw[(lg*4+r)*40 + 16 + lr] = tobf(p1v[r]);
    }
    __syncthreads();
    bf16x8 pa = *reinterpret_cast<const bf16x8*>(pw + lr*40 + lg*8);
    #pragma unroll
    for (int dt=0;dt<4;dt++){
      bf16x8 vf = *reinterpret_cast<const bf16x8*>(
          Vbase + (long)(dt*16 + lr)*NS + k0 + lg*8);
      cacc[dt] = mfma16(pa, vf, cacc[dt]);
    }
    __syncthreads();
  }

  #pragma unroll
  for (int r=0;r<4;r++){
    float inv = 1.f/lsum[r];
    #pragma unroll
    for (int dt=0;dt<4;dt++) cacc[dt][r] *= inv;
  }
  long crow = (long)b*NS + q0;
  #pragma unroll
  for (int dt=0;dt<4;dt++)
    #pragma unroll
    for (int r=0;r<4;r++)
      ctx[(crow + lg*4 + r)*ND + h*NHD + dt*16 + lr] = tobf(cacc[dt][r]);
}

// ---------- LayerNorm kernels (fp32, fused residual) ----------
DEV void block_red2(float& s1, float& s2){
  __shared__ float red[8];
  #pragma unroll
  for (int o=32;o;o>>=1){ s1 += __shfl_down(s1,o); s2 += __shfl_down(s2,o); }
  int wid = threadIdx.x>>6, lane = threadIdx.x&63;
  if (lane==0){ red[wid]=s1; red[4+wid]=s2; }
  __syncthreads();
  s1 = red[0]+red[1]+red[2]+red[3];
  s2 = red[4]+red[5]+red[6]+red[7];
}

__global__ __launch_bounds__(256) void ln1_k(const float* __restrict__ ctxO,
    const float* __restrict__ wh, const float* __restrict__ eh,
    const float* __restrict__ g, const float* __restrict__ be,
    float* __restrict__ outF, bf16* __restrict__ outB){
  const int row = blockIdx.x;
  const int b = row / NS, s = row % NS;
  const float* resid = (s < NSW) ? wh + ((long)(b*NSW + s))*ND
                                 : eh + ((long)(b*NSE + (s-NSW)))*ND;
  const int t = threadIdx.x;
  float4 xv = reinterpret_cast<const float4*>(ctxO + (long)row*ND)[t];
  float4 rv = reinterpret_cast<const float4*>(resid)[t];
  float4 x = make_float4(xv.x+rv.x, xv.y+rv.y, xv.z+rv.z, xv.w+rv.w);
  float s1 = x.x+x.y+x.z+x.w;
  float s2 = x.x*x.x + x.y*x.y + x.z*x.z + x.w*x.w;
  block_red2(s1, s2);
  float mean = s1 * (1.f/ND);
  float var  = s2 * (1.f/ND) - mean*mean;
  float rstd = rsqrtf(var + 1e-12f);
  float4 gv = reinterpret_cast<const float4*>(g)[t];
  float4 bv = reinterpret_cast<const float4*>(be)[t];
  float4 y = make_float4(gv.x*(x.x-mean)*rstd + bv.x,
                         gv.y*(x.y-mean)*rstd + bv.y,
                         gv.z*(x.z-mean)*rstd + bv.z,
                         gv.w*(x.w-mean)*rstd + bv.w);
  reinterpret_cast<float4*>(outF + (long)row*ND)[t] = y;
  PK4 p; p.h[0]=tobf(y.x); p.h[1]=tobf(y.y); p.h[2]=tobf(y.z); p.h[3]=tobf(y.w);
  reinterpret_cast<short4*>(outB + (long)row*ND)[t] = p.s;
}

__global__ __launch_bounds__(256) void ln2_k(const float* __restrict__ ffo,
    const float* __restrict__ attnF, const float* __restrict__ g,
    const float* __restrict__ be, float* __restrict__ out){
  const int row = blockIdx.x;
  const int b = row / NS, s = row % NS;
  const int t = threadIdx.x;
  float4 xv = reinterpret_cast<const float4*>(ffo + (long)row*ND)[t];
  float4 rv = reinterpret_cast<const float4*>(attnF + (long)row*ND)[t];
  float4 x = make_float4(xv.x+rv.x, xv.y+rv.y, xv.z+rv.z, xv.w+rv.w);
  float s1 = x.x+x.y+x.z+x.w;
  float s2 = x.x*x.x + x.y*x.y + x.z*x.z + x.w*x.w;
  block_red2(s1, s2);
  float mean = s1 * (1.f/ND);
  float var  = s2 * (1.f/ND) - mean*mean;
  float rstd = rsqrtf(var + 1e-12f);
  float4 gv = reinterpret_cast<const float4*>(g)[t];
  float4 bv = reinterpret_cast<const float4*>(be)[t];
  float4 y = make_float4(gv.x*(x.x-mean)*rstd + bv.x,
                         gv.y*(x.y-mean)*rstd + bv.y,
                         gv.z*(x.z-mean)*rstd + bv.z,
                         gv.w*(x.w-mean)*rstd + bv.w);
  float* op = (s < NSW) ? out + ((long)(b*NSW+s))*ND
                        : out + (long)NB*NSW*ND + ((long)(b*NSE + (s-NSW)))*ND;
  reinterpret_cast<float4*>(op)[t] = y;
}

// ---------- host ----------
extern "C" void kernel_launch(void* const* d_in, const int* in_sizes, int n_in,
                              void* d_out, int out_size, void* d_ws, size_t ws_size,
                              hipStream_t stream){
  (void)in_sizes; (void)n_in; (void)out_size; (void)ws_size;
  const float* wh   = (const float*)d_in[0];
  const float* eh   = (const float*)d_in[1];
  const float* wm   = (const float*)d_in[2];
  const float* em   = (const float*)d_in[3];
  const float* Wq   = (const float*)d_in[4];   const float* bq   = (const float*)d_in[5];
  const float* Ww2e = (const float*)d_in[6];   const float* bw2e = (const float*)d_in[7];
  const float* We2w = (const float*)d_in[8];   const float* be2w = (const float*)d_in[9];
  const float* We2e = (const float*)d_in[10];  const float* be2e = (const float*)d_in[11];
  const float* Wk   = (const float*)d_in[12];  const float* bk   = (const float*)d_in[13];
  const float* Wv   = (const float*)d_in[14];  const float* bv   = (const float*)d_in[15];
  const float* Wo   = (const float*)d_in[16];  const float* bo   = (const float*)d_in[17];
  const float* g1   = (const float*)d_in[18];  const float* b1   = (const float*)d_in[19];
  const float* Wi   = (const float*)d_in[20];  const float* bi   = (const float*)d_in[21];
  const float* Wout = (const float*)d_in[22];  const float* bout = (const float*)d_in[23];
  const float* g2   = (const float*)d_in[24];  const float* b2   = (const float*)d_in[25];
  float* out = (float*)d_out;

  char* ws = (char*)d_ws;
  size_t off = 0;
  auto alloc = [&](size_t bytes)->char*{
    char* p = ws + off; off += (bytes + 255) & ~(size_t)255; return p;
  };

  bf16* hid   = (bf16*)alloc((size_t)NB*NS*ND*2);
  bf16* whb   = (bf16*)alloc((size_t)NB*NSW*ND*2);
  bf16* ehb   = (bf16*)alloc((size_t)NB*NSE*ND*2);
  bf16* WqT   = (bf16*)alloc((size_t)ND*ND*2);
  bf16* Ww2eT = (bf16*)alloc((size_t)ND*ND*2);
  bf16* We2wT = (bf16*)alloc((size_t)ND*ND*2);
  bf16* We2eT = (bf16*)alloc((size_t)ND*ND*2);
  bf16* WkT   = (bf16*)alloc((size_t)ND*ND*2);
  bf16* WvT   = (bf16*)alloc((size_t)ND*ND*2);
  bf16* WoT   = (bf16*)alloc((size_t)ND*ND*2);
  bf16* WiT   = (bf16*)alloc((size_t)NFF*ND*2);
  bf16* WoutT = (bf16*)alloc((size_t)ND*NFF*2);

  // union block: {Qw2w,Qw2e,Qe2w,Qe2e,K,Vt} later reused as FFN 'inter'
  char* u1 = alloc((size_t)41943040);
  bf16* Qw2w = (bf16*)u1;
  bf16* Qw2e = Qw2w + (size_t)NB*NSW*ND;
  bf16* Qe2w = Qw2e + (size_t)NB*NSW*ND;
  bf16* Qe2e = Qe2w + (size_t)NB*NSE*ND;
  bf16* Kb   = Qe2e + (size_t)NB*NSE*ND;
  bf16* Vt   = Kb   + (size_t)NB*NS*ND;
  bf16* inter = (bf16*)u1;            // aliases Q/K/V (dead by FFN time)

  bf16*  ctx   = (bf16*)alloc((size_t)NB*NS*ND*2);
  float* ctxO  = (float*)alloc((size_t)NB*NS*ND*4);   // also reused as ffo
  float* ffo   = ctxO;
  float* attnF = (float*)alloc((size_t)NB*NS*ND*4);
  bf16*  attnB = (bf16*)alloc((size_t)NB*NS*ND*2);

  dim3 tb(32,8);
  cast_word_k<<<4096, 256, 0, stream>>>(wh, whb, hid);
  cast_ent_k <<<1024, 256, 0, stream>>>(eh, ehb, hid);
  transpose_cast_k<<<dim3(32,32),  tb, 0, stream>>>(Wq,   WqT,   ND, ND);
  transpose_cast_k<<<dim3(32,32),  tb, 0, stream>>>(Ww2e, Ww2eT, ND, ND);
  transpose_cast_k<<<dim3(32,32),  tb, 0, stream>>>(We2w, We2wT, ND, ND);
  transpose_cast_k<<<dim3(32,32),  tb, 0, stream>>>(We2e, We2eT, ND, ND);
  transpose_cast_k<<<dim3(32,32),  tb, 0, stream>>>(Wk,   WkT,   ND, ND);
  transpose_cast_k<<<dim3(32,32),  tb, 0, stream>>>(Wv,   WvT,   ND, ND);
  transpose_cast_k<<<dim3(32,32),  tb, 0, stream>>>(Wo,   WoT,   ND, ND);
  transpose_cast_k<<<dim3(128,32), tb, 0, stream>>>(Wi,   WiT,   ND, NFF);
  transpose_cast_k<<<dim3(32,128), tb, 0, stream>>>(Wout, WoutT, NFF, ND);

  gemm_bt_k<0><<<dim3(8, 32), 256, 0, stream>>>(whb, WqT,   bq,   Qw2w, NB*NSW, ND, ND);
  gemm_bt_k<0><<<dim3(8, 32), 256, 0, stream>>>(whb, Ww2eT, bw2e, Qw2e, NB*NSW, ND, ND);
  gemm_bt_k<0><<<dim3(8, 8),  256, 0, stream>>>(ehb, We2wT, be2w, Qe2w, NB*NSE, ND, ND);
  gemm_bt_k<0><<<dim3(8, 8),  256, 0, stream>>>(ehb, We2eT, be2e, Qe2e, NB*NSE, ND, ND);
  gemm_bt_k<0><<<dim3(8, 40), 256, 0, stream>>>(hid, WkT,   bk,   Kb,   NB*NS,  ND, ND);
  gemm_bt_k<1><<<dim3(8, 40), 256, 0, stream>>>(hid, WvT,   bv,   Vt,   NB*NS,  ND, ND);

  attn_k<<<1280, 256, 0, stream>>>(Qw2w, Qw2e, Qe2w, Qe2e, Kb, Vt, wm, em, ctx);

  gemm_bt_k<2><<<dim3(8, 40), 256, 0, stream>>>(ctx, WoT, bo, ctxO, NB*NS, ND, ND);
  ln1_k<<<5120, 256, 0, stream>>>(ctxO, wh, eh, g1, b1, attnF, attnB);
  gemm_bt_k<3><<<dim3(32, 40), 256, 0, stream>>>(attnB, WiT, bi, inter, NB*NS, NFF, ND);
  gemm_bt_k<2><<<dim3(8, 40), 256, 0, stream>>>(inter, WoutT, bout, ffo, NB*NS, ND, NFF);
  ln2_k<<<5120, 256, 0, stream>>>(ffo, attnF, g2, b2, out);
}

// Round 2
// 605.922 us; speedup vs baseline: 1.1862x; 1.1862x over previous
//
#include <hip/hip_runtime.h>
#include <hip/hip_bf16.h>
#include <stdint.h>
#include <math.h>

#define DEV __device__ __forceinline__

using bf16 = __hip_bfloat16;
typedef __attribute__((ext_vector_type(8))) short bf16x8;
typedef __attribute__((ext_vector_type(4))) float f32x4;

static constexpr int NB  = 8;
static constexpr int NSW = 512;
static constexpr int NSE = 128;
static constexpr int ND  = 1024;
static constexpr int NH  = 16;
static constexpr int NFF = 4096;
static constexpr int NS  = NSW + NSE;   // 640
static constexpr int NHD = 64;

DEV f32x4 mfma16(bf16x8 a, bf16x8 b, f32x4 c){
  return __builtin_amdgcn_mfma_f32_16x16x32_bf16(a, b, c, 0, 0, 0);
}

DEV void gload16(const bf16* g, bf16* l){
  __builtin_amdgcn_global_load_lds((const __attribute__((address_space(1))) void*)g,
                                   (__attribute__((address_space(3))) void*)l,
                                   16, 0, 0);
}

DEV bf16 tobf(float f){ return __float2bfloat16(f); }

union PK4 { bf16 h[4]; short4 s; };

// ---------- casts: fp32 -> bf16, plus build concatenated hidden ----------
__global__ __launch_bounds__(256) void cast_word_k(const float* __restrict__ wh,
                                                   bf16* __restrict__ whb,
                                                   bf16* __restrict__ hid){
  long i = ((long)blockIdx.x*256 + threadIdx.x)*4;
  float4 v = *reinterpret_cast<const float4*>(wh + i);
  PK4 p; p.h[0]=tobf(v.x); p.h[1]=tobf(v.y); p.h[2]=tobf(v.z); p.h[3]=tobf(v.w);
  *reinterpret_cast<short4*>(whb + i) = p.s;
  long row = i >> 10; int c = (int)(i & 1023);
  int b = (int)(row >> 9), s = (int)(row & 511);
  *reinterpret_cast<short4*>(hid + ((long)(b*NS + s) << 10) + c) = p.s;
}

__global__ __launch_bounds__(256) void cast_ent_k(const float* __restrict__ eh,
                                                  bf16* __restrict__ ehb,
                                                  bf16* __restrict__ hid){
  long i = ((long)blockIdx.x*256 + threadIdx.x)*4;
  float4 v = *reinterpret_cast<const float4*>(eh + i);
  PK4 p; p.h[0]=tobf(v.x); p.h[1]=tobf(v.y); p.h[2]=tobf(v.z); p.h[3]=tobf(v.w);
  *reinterpret_cast<short4*>(ehb + i) = p.s;
  long row = i >> 10; int c = (int)(i & 1023);
  int b = (int)(row >> 7), s = (int)(row & 127);
  *reinterpret_cast<short4*>(hid + ((long)(b*NS + NSW + s) << 10) + c) = p.s;
}

// ---------- batched 1024x1024 weight transpose+cast ----------
struct TP7 { const float* src[7]; bf16* dst[7]; };

__global__ void transpose7_k(TP7 tp){
  __shared__ float tile[32][33];
  const float* in = tp.src[blockIdx.z];
  bf16* out = tp.dst[blockIdx.z];
  const int c0 = blockIdx.x*32, r0 = blockIdx.y*32;
  const int tx = threadIdx.x, ty = threadIdx.y;
  #pragma unroll
  for (int i=0;i<4;i++)
    tile[ty + i*8][tx] = in[(long)(r0 + ty + i*8)*1024 + c0 + tx];
  __syncthreads();
  #pragma unroll
  for (int i=0;i<4;i++){
    int rr = ty + i*8;
    out[(long)(c0 + rr)*1024 + r0 + tx] = tobf(tile[tx][rr]);
  }
}

// generic (R,C) fp32 -> (C,R) bf16
__global__ void transpose_cast_k(const float* __restrict__ in, bf16* __restrict__ out,
                                 int R, int C){
  __shared__ float tile[32][33];
  const int c0 = blockIdx.x*32, r0 = blockIdx.y*32;
  const int tx = threadIdx.x, ty = threadIdx.y;
  #pragma unroll
  for (int i=0;i<4;i++)
    tile[ty + i*8][tx] = in[(long)(r0 + ty + i*8)*C + c0 + tx];
  __syncthreads();
  #pragma unroll
  for (int i=0;i<4;i++){
    int rr = ty + i*8;
    out[(long)(c0 + rr)*R + r0 + tx] = tobf(tile[tx][rr]);
  }
}

__global__ void bias_concat_k(const float* __restrict__ bq, const float* __restrict__ bw2e,
                              const float* __restrict__ be2w, const float* __restrict__ be2e,
                              const float* __restrict__ bk, const float* __restrict__ bv,
                              float* __restrict__ bQw, float* __restrict__ bQe,
                              float* __restrict__ bKV){
  int i = blockIdx.x*256 + threadIdx.x;
  bQw[i] = bq[i];   bQw[1024+i] = bw2e[i];
  bQe[i] = be2w[i]; bQe[1024+i] = be2e[i];
  bKV[i] = bk[i];   bKV[1024+i] = bv[i];
}

// ---------- GEMM: C(M,N) = A(M,K) @ Bt(N,K)^T + bias, bf16 MFMA ----------
// EPI: 0 = bf16 out (M,N); 2 = fp32 out (M,N); 3 = GELU(exact)->bf16 (M,N);
//      4 = fused KV: col<1024 -> bf16 (M,2048) at Cout, col>=1024 -> Vt(B,H,64,NS) at Cout2
template<int EPI>
__global__ __launch_bounds__(256) void gemm_bt_k(const bf16* __restrict__ A,
                                                 const bf16* __restrict__ Bt,
                                                 const float* __restrict__ bias,
                                                 void* __restrict__ Cout,
                                                 void* __restrict__ Cout2,
                                                 int M, int N, int K){
  __shared__ __align__(16) bf16 As[128*64];
  __shared__ __align__(16) bf16 Bs[128*64];
  const int tid = threadIdx.x;

  // bijective XCD swizzle (m204)
  const int nwg = gridDim.x*gridDim.y;
  const int orig = blockIdx.y*gridDim.x + blockIdx.x;
  const int qq = nwg >> 3, rr8 = nwg & 7;
  const int xcd = orig & 7, idx = orig >> 3;
  const int wg = (xcd < rr8 ? xcd*(qq+1) : rr8*(qq+1) + (xcd-rr8)*qq) + idx;
  const int m0 = (wg / gridDim.x)*128, n0 = (wg % gridDim.x)*128;

  const int wid = tid>>6, lane = tid&63;
  const int wr = wid>>1, wc = wid&1;
  const int lr = lane&15, lg = lane>>4;

  const f32x4 zero = {0.f,0.f,0.f,0.f};
  f32x4 acc[4][4];
  #pragma unroll
  for (int m=0;m<4;m++)
    #pragma unroll
    for (int n=0;n<4;n++) acc[m][n] = zero;

  for (int kt=0; kt<K; kt+=64){
    #pragma unroll
    for (int i=0;i<4;i++){
      int idx2 = i*256 + tid;
      int row = idx2>>3, kc = idx2&7;
      gload16(A + (long)(m0+row)*K + kt + kc*8, As + idx2*8);
    }
    #pragma unroll
    for (int i=0;i<4;i++){
      int idx2 = i*256 + tid;
      int row = idx2>>3, kc = idx2&7;
      gload16(Bt + (long)(n0+row)*K + kt + kc*8, Bs + idx2*8);
    }
    __syncthreads();
    #pragma unroll
    for (int ks=0; ks<2; ks++){
      bf16x8 af[4], bg[4];
      #pragma unroll
      for (int m=0;m<4;m++)
        af[m] = *reinterpret_cast<const bf16x8*>(As + (wr*64 + m*16 + lr)*64 + ks*32 + lg*8);
      #pragma unroll
      for (int n=0;n<4;n++)
        bg[n] = *reinterpret_cast<const bf16x8*>(Bs + (wc*64 + n*16 + lr)*64 + ks*32 + lg*8);
      __builtin_amdgcn_s_setprio(1);
      #pragma unroll
      for (int m=0;m<4;m++)
        #pragma unroll
        for (int n=0;n<4;n++)
          acc[m][n] = mfma16(af[m], bg[n], acc[m][n]);
      __builtin_amdgcn_s_setprio(0);
    }
    __syncthreads();
  }

  #pragma unroll
  for (int m=0;m<4;m++){
    const int rbase = m0 + wr*64 + m*16 + lg*4;
    #pragma unroll
    for (int n=0;n<4;n++){
      const int col = n0 + wc*64 + n*16 + lr;
      const float bsv = bias[col];
      #pragma unroll
      for (int r=0;r<4;r++){
        const int rw = rbase + r;
        float v = acc[m][n][r] + bsv;
        if constexpr (EPI == 0){
          ((bf16*)Cout)[(long)rw*N + col] = tobf(v);
        } else if constexpr (EPI == 2){
          ((float*)Cout)[(long)rw*N + col] = v;
        } else if constexpr (EPI == 3){
          float ge = 0.5f*v*(1.0f + erff(v*0.70710678118654752f));
          ((bf16*)Cout)[(long)rw*N + col] = tobf(ge);
        } else {  // EPI == 4
          if (col < 1024){
            ((bf16*)Cout)[(long)rw*2048 + col] = tobf(v);
          } else {
            int bb = rw / NS, ss = rw % NS, hh = (col-1024) >> 6, dd = (col-1024) & 63;
            ((bf16*)Cout2)[((long)((bb*NH + hh)*NHD + dd))*NS + ss] = tobf(v);
          }
        }
      }
    }
  }
}

// ---------- fused entity-aware flash attention ----------
// One wave = 32 queries of one (b,h); online softmax over 20 tiles of 32 keys.
// No block barriers: P-tile LDS is private per wave (intra-wave lgkmcnt ordering only).
__global__ __launch_bounds__(256) void attn_k(
    const bf16* __restrict__ Qw,  // (B*SW,2048): [:,0:1024)=w2w, [:,1024:)=w2e
    const bf16* __restrict__ Qe,  // (B*SE,2048): [:,0:1024)=e2w, [:,1024:)=e2e
    const bf16* __restrict__ KV,  // (B*NS,2048): [:,0:1024)=K
    const bf16* __restrict__ Vt,  // (B,H,64,NS)
    const float* __restrict__ wm, const float* __restrict__ em,
    bf16* __restrict__ ctx){      // (B*NS,1024)
  __shared__ __align__(16) bf16 Plds[4][2][16*40];
  const int tid = threadIdx.x, wid = tid>>6, lane = tid&63;
  const int lr = lane&15, lg = lane>>4;
  const int w   = blockIdx.x*4 + wid;
  const int b   = w / (NH*20);
  const int rem = w % (NH*20);
  const int h   = rem / 20;
  const int q0  = (rem % 20)*32;

  const bf16* Qbase; long qrow0;
  if (q0 < NSW){ Qbase = Qw; qrow0 = (long)b*NSW + q0; }
  else         { Qbase = Qe; qrow0 = (long)b*NSE + (q0 - NSW); }

  bf16x8 qA[2][2], qB[2][2];   // [m][dc]: A = "2w" half, B = "2e" half
  #pragma unroll
  for (int m=0;m<2;m++)
    #pragma unroll
    for (int dc=0; dc<2; dc++){
      long o = (qrow0 + m*16 + lr)*2048 + h*NHD + dc*32 + lg*8;
      qA[m][dc] = *reinterpret_cast<const bf16x8*>(Qbase + o);
      qB[m][dc] = *reinterpret_cast<const bf16x8*>(Qbase + o + 1024);
    }

  const f32x4 zero = {0.f,0.f,0.f,0.f};
  f32x4 cacc[2][4];
  float mrow[2][4], lsum[2][4];
  #pragma unroll
  for (int m=0;m<2;m++){
    #pragma unroll
    for (int dt=0;dt<4;dt++) cacc[m][dt] = zero;
    #pragma unroll
    for (int r=0;r<4;r++){ mrow[m][r] = -1e30f; lsum[m][r] = 0.f; }
  }

  const bf16* Kbase = KV + (long)b*NS*2048 + h*NHD;
  const bf16* Vbase = Vt + (long)((b*NH + h)*NHD)*NS;

  for (int kt=0; kt<20; kt++){
    const int k0 = kt*32;
    const bool word = (k0 < NSW);

    // issue all K and V loads up front (latency hides under QK + softmax)
    bf16x8 kf[2][2], vf[4];
    #pragma unroll
    for (int sub=0;sub<2;sub++)
      #pragma unroll
      for (int dc=0;dc<2;dc++)
        kf[sub][dc] = *reinterpret_cast<const bf16x8*>(
            Kbase + (long)(k0 + sub*16 + lr)*2048 + dc*32 + lg*8);
    #pragma unroll
    for (int dt=0;dt<4;dt++)
      vf[dt] = *reinterpret_cast<const bf16x8*>(
          Vbase + (long)(dt*16 + lr)*NS + k0 + lg*8);

    float msk0, msk1;
    { int k = k0 + lr;
      msk0 = word ? wm[b*NSW + k]      : em[b*NSE + (k - NSW)];
      msk1 = word ? wm[b*NSW + k + 16] : em[b*NSE + (k + 16 - NSW)];
    }

    f32x4 sc[2][2];
    #pragma unroll
    for (int m=0;m<2;m++){ sc[m][0]=zero; sc[m][1]=zero; }
    __builtin_amdgcn_s_setprio(1);
    #pragma unroll
    for (int m=0;m<2;m++)
      #pragma unroll
      for (int sub=0;sub<2;sub++)
        #pragma unroll
        for (int dc=0;dc<2;dc++){
          const bf16x8 q = word ? qA[m][dc] : qB[m][dc];
          sc[m][sub] = mfma16(q, kf[sub][dc], sc[m][sub]);
        }
    __builtin_amdgcn_s_setprio(0);

    #pragma unroll
    for (int m=0;m<2;m++){
      bf16* pw = &Plds[wid][m][0];
      #pragma unroll
      for (int r=0;r<4;r++){
        float s0 = sc[m][0][r]*0.125f + msk0;
        float s1 = sc[m][1][r]*0.125f + msk1;
        float t = fmaxf(s0, s1);
        #pragma unroll
        for (int o=8;o;o>>=1) t = fmaxf(t, __shfl_xor(t, o, 16));
        float mn = fmaxf(mrow[m][r], t);
        float al = __expf(mrow[m][r] - mn);
        mrow[m][r] = mn;
        float p0 = __expf(s0 - mn), p1 = __expf(s1 - mn);
        float ps = p0 + p1;
        #pragma unroll
        for (int o=8;o;o>>=1) ps += __shfl_xor(ps, o, 16);
        lsum[m][r] = lsum[m][r]*al + ps;
        pw[(lg*4+r)*40 + lr]      = tobf(p0);
        pw[(lg*4+r)*40 + 16 + lr] = tobf(p1);
        #pragma unroll
        for (int dt=0;dt<4;dt++) cacc[m][dt][r] *= al;
      }
    }

    __builtin_amdgcn_s_setprio(1);
    #pragma unroll
    for (int m=0;m<2;m++){
      bf16x8 pa = *reinterpret_cast<const bf16x8*>(&Plds[wid][m][0] + lr*40 + lg*8);
      #pragma unroll
      for (int dt=0;dt<4;dt++)
        cacc[m][dt] = mfma16(pa, vf[dt], cacc[m][dt]);
    }
    __builtin_amdgcn_s_setprio(0);
  }

  #pragma unroll
  for (int m=0;m<2;m++)
    #pragma unroll
    for (int r=0;r<4;r++){
      float inv = 1.f/lsum[m][r];
      #pragma unroll
      for (int dt=0;dt<4;dt++) cacc[m][dt][r] *= inv;
    }
  long crow = (long)b*NS + q0;
  #pragma unroll
  for (int m=0;m<2;m++)
    #pragma unroll
    for (int dt=0;dt<4;dt++)
      #pragma unroll
      for (int r=0;r<4;r++)
        ctx[(crow + m*16 + lg*4 + r)*ND + h*NHD + dt*16 + lr] = tobf(cacc[m][dt][r]);
}

// ---------- LayerNorm kernels (fp32, fused residual) ----------
DEV void block_red2(float& s1, float& s2){
  __shared__ float red[8];
  #pragma unroll
  for (int o=32;o;o>>=1){ s1 += __shfl_down(s1,o); s2 += __shfl_down(s2,o); }
  int wid = threadIdx.x>>6, lane = threadIdx.x&63;
  if (lane==0){ red[wid]=s1; red[4+wid]=s2; }
  __syncthreads();
  s1 = red[0]+red[1]+red[2]+red[3];
  s2 = red[4]+red[5]+red[6]+red[7];
}

__global__ __launch_bounds__(256) void ln1_k(const float* __restrict__ ctxO,
    const float* __restrict__ wh, const float* __restrict__ eh,
    const float* __restrict__ g, const float* __restrict__ be,
    float* __restrict__ outF, bf16* __restrict__ outB){
  const int row = blockIdx.x;
  const int b = row / NS, s = row % NS;
  const float* resid = (s < NSW) ? wh + ((long)(b*NSW + s))*ND
                                 : eh + ((long)(b*NSE + (s-NSW)))*ND;
  const int t = threadIdx.x;
  float4 xv = reinterpret_cast<const float4*>(ctxO + (long)row*ND)[t];
  float4 rv = reinterpret_cast<const float4*>(resid)[t];
  float4 x = make_float4(xv.x+rv.x, xv.y+rv.y, xv.z+rv.z, xv.w+rv.w);
  float s1 = x.x+x.y+x.z+x.w;
  float s2 = x.x*x.x + x.y*x.y + x.z*x.z + x.w*x.w;
  block_red2(s1, s2);
  float mean = s1 * (1.f/ND);
  float var  = s2 * (1.f/ND) - mean*mean;
  float rstd = rsqrtf(var + 1e-12f);
  float4 gv = reinterpret_cast<const float4*>(g)[t];
  float4 bv = reinterpret_cast<const float4*>(be)[t];
  float4 y = make_float4(gv.x*(x.x-mean)*rstd + bv.x,
                         gv.y*(x.y-mean)*rstd + bv.y,
                         gv.z*(x.z-mean)*rstd + bv.z,
                         gv.w*(x.w-mean)*rstd + bv.w);
  reinterpret_cast<float4*>(outF + (long)row*ND)[t] = y;
  PK4 p; p.h[0]=tobf(y.x); p.h[1]=tobf(y.y); p.h[2]=tobf(y.z); p.h[3]=tobf(y.w);
  reinterpret_cast<short4*>(outB + (long)row*ND)[t] = p.s;
}

__global__ __launch_bounds__(256) void ln2_k(const float* __restrict__ ffo,
    const float* __restrict__ attnF, const float* __restrict__ g,
    const float* __restrict__ be, float* __restrict__ out){
  const int row = blockIdx.x;
  const int b = row / NS, s = row % NS;
  const int t = threadIdx.x;
  float4 xv = reinterpret_cast<const float4*>(ffo + (long)row*ND)[t];
  float4 rv = reinterpret_cast<const float4*>(attnF + (long)row*ND)[t];
  float4 x = make_float4(xv.x+rv.x, xv.y+rv.y, xv.z+rv.z, xv.w+rv.w);
  float s1 = x.x+x.y+x.z+x.w;
  float s2 = x.x*x.x + x.y*x.y + x.z*x.z + x.w*x.w;
  block_red2(s1, s2);
  float mean = s1 * (1.f/ND);
  float var  = s2 * (1.f/ND) - mean*mean;
  float rstd = rsqrtf(var + 1e-12f);
  float4 gv = reinterpret_cast<const float4*>(g)[t];
  float4 bv = reinterpret_cast<const float4*>(be)[t];
  float4 y = make_float4(gv.x*(x.x-mean)*rstd + bv.x,
                         gv.y*(x.y-mean)*rstd + bv.y,
                         gv.z*(x.z-mean)*rstd + bv.z,
                         gv.w*(x.w-mean)*rstd + bv.w);
  float* op = (s < NSW) ? out + ((long)(b*NSW+s))*ND
                        : out + (long)NB*NSW*ND + ((long)(b*NSE + (s-NSW)))*ND;
  reinterpret_cast<float4*>(op)[t] = y;
}

// ---------- host ----------
extern "C" void kernel_launch(void* const* d_in, const int* in_sizes, int n_in,
                              void* d_out, int out_size, void* d_ws, size_t ws_size,
                              hipStream_t stream){
  (void)in_sizes; (void)n_in; (void)out_size; (void)ws_size;
  const float* wh   = (const float*)d_in[0];
  const float* eh   = (const float*)d_in[1];
  const float* wm   = (const float*)d_in[2];
  const float* em   = (const float*)d_in[3];
  const float* Wq   = (const float*)d_in[4];   const float* bq   = (const float*)d_in[5];
  const float* Ww2e = (const float*)d_in[6];   const float* bw2e = (const float*)d_in[7];
  const float* We2w = (const float*)d_in[8];   const float* be2w = (const float*)d_in[9];
  const float* We2e = (const float*)d_in[10];  const float* be2e = (const float*)d_in[11];
  const float* Wk   = (const float*)d_in[12];  const float* bk   = (const float*)d_in[13];
  const float* Wv   = (const float*)d_in[14];  const float* bv   = (const float*)d_in[15];
  const float* Wo   = (const float*)d_in[16];  const float* bo   = (const float*)d_in[17];
  const float* g1   = (const float*)d_in[18];  const float* b1   = (const float*)d_in[19];
  const float* Wi   = (const float*)d_in[20];  const float* bi   = (const float*)d_in[21];
  const float* Wout = (const float*)d_in[22];  const float* bout = (const float*)d_in[23];
  const float* g2   = (const float*)d_in[24];  const float* b2   = (const float*)d_in[25];
  float* out = (float*)d_out;

  char* ws = (char*)d_ws;
  size_t off = 0;
  auto alloc = [&](size_t bytes)->char*{
    char* p = ws + off; off += (bytes + 255) & ~(size_t)255; return p;
  };

  bf16* hid   = (bf16*)alloc((size_t)NB*NS*ND*2);
  bf16* whb   = (bf16*)alloc((size_t)NB*NSW*ND*2);
  bf16* ehb   = (bf16*)alloc((size_t)NB*NSE*ND*2);
  bf16* WqwT  = (bf16*)alloc((size_t)2048*ND*2);   // [Wq^T ; Ww2e^T]
  bf16* WqeT  = (bf16*)alloc((size_t)2048*ND*2);   // [We2w^T ; We2e^T]
  bf16* WkvT  = (bf16*)alloc((size_t)2048*ND*2);   // [Wk^T ; Wv^T]
  bf16* WoT   = (bf16*)alloc((size_t)ND*ND*2);
  bf16* WiT   = (bf16*)alloc((size_t)NFF*ND*2);
  bf16* WoutT = (bf16*)alloc((size_t)ND*NFF*2);
  float* bQw  = (float*)alloc(2048*4);
  float* bQe  = (float*)alloc(2048*4);
  float* bKV  = (float*)alloc(2048*4);

  // union region: {Qw, Qe, KV, Vt} reused as {inter, attnB} after attention
  char* u1 = alloc((size_t)52428800);
  bf16* Qwb = (bf16*)u1;                               // (B*SW, 2048) = 16 MB
  bf16* Qeb = Qwb + (size_t)NB*NSW*2048;               // (B*SE, 2048) = 4 MB
  bf16* KVb = Qeb + (size_t)NB*NSE*2048;               // (B*NS, 2048) = 20 MB
  bf16* Vt  = KVb + (size_t)NB*NS*2048;                // (B,H,64,NS) = 10 MB
  bf16* inter = (bf16*)u1;                             // (B*NS, 4096) = 40 MB
  bf16* attnB = (bf16*)(u1 + (size_t)41943040);        // (B*NS, 1024) = 10 MB (over Vt)

  bf16*  ctx   = (bf16*)alloc((size_t)NB*NS*ND*2);
  float* ctxO  = (float*)alloc((size_t)NB*NS*ND*4);    // reused as ffo
  float* ffo   = ctxO;
  float* attnF = (float*)alloc((size_t)NB*NS*ND*4);

  dim3 tb(32,8);
  cast_word_k<<<4096, 256, 0, stream>>>(wh, whb, hid);
  cast_ent_k <<<1024, 256, 0, stream>>>(eh, ehb, hid);

  TP7 tp;
  tp.src[0]=Wq;   tp.dst[0]=WqwT;
  tp.src[1]=Ww2e; tp.dst[1]=WqwT + (size_t)1024*1024;
  tp.src[2]=We2w; tp.dst[2]=WqeT;
  tp.src[3]=We2e; tp.dst[3]=WqeT + (size_t)1024*1024;
  tp.src[4]=Wk;   tp.dst[4]=WkvT;
  tp.src[5]=Wv;   tp.dst[5]=WkvT + (size_t)1024*1024;
  tp.src[6]=Wo;   tp.dst[6]=WoT;
  transpose7_k<<<dim3(32,32,7), tb, 0, stream>>>(tp);
  transpose_cast_k<<<dim3(128,32), tb, 0, stream>>>(Wi,   WiT,   ND, NFF);
  transpose_cast_k<<<dim3(32,128), tb, 0, stream>>>(Wout, WoutT, NFF, ND);
  bias_concat_k<<<4, 256, 0, stream>>>(bq, bw2e, be2w, be2e, bk, bv, bQw, bQe, bKV);

  gemm_bt_k<0><<<dim3(16,32), 256, 0, stream>>>(whb, WqwT, bQw, Qwb, nullptr, NB*NSW, 2048, ND);
  gemm_bt_k<0><<<dim3(16, 8), 256, 0, stream>>>(ehb, WqeT, bQe, Qeb, nullptr, NB*NSE, 2048, ND);
  gemm_bt_k<4><<<dim3(16,40), 256, 0, stream>>>(hid, WkvT, bKV, KVb, Vt,      NB*NS,  2048, ND);

  attn_k<<<640, 256, 0, stream>>>(Qwb, Qeb, KVb, Vt, wm, em, ctx);

  gemm_bt_k<2><<<dim3(8,40),  256, 0, stream>>>(ctx,   WoT,   bo,   ctxO,  nullptr, NB*NS, ND,  ND);
  ln1_k<<<5120, 256, 0, stream>>>(ctxO, wh, eh, g1, b1, attnF, attnB);
  gemm_bt_k<3><<<dim3(32,40), 256, 0, stream>>>(attnB, WiT,   bi,   inter, nullptr, NB*NS, NFF, ND);
  gemm_bt_k<2><<<dim3(8,40),  256, 0, stream>>>(inter, WoutT, bout, ffo,   nullptr, NB*NS, ND,  NFF);
  ln2_k<<<5120, 256, 0, stream>>>(ffo, attnF, g2, b2, out);
}

// Round 4
// 563.020 us; speedup vs baseline: 1.2766x; 1.0762x over previous
//
#include <hip/hip_runtime.h>
#include <hip/hip_bf16.h>
#include <stdint.h>
#include <math.h>

#define DEV __device__ __forceinline__

using bf16 = __hip_bfloat16;
typedef __attribute__((ext_vector_type(8))) short bf16x8;
typedef __attribute__((ext_vector_type(4))) float f32x4;

static constexpr int NB  = 8;
static constexpr int NSW = 512;
static constexpr int NSE = 128;
static constexpr int ND  = 1024;
static constexpr int NH  = 16;
static constexpr int NFF = 4096;
static constexpr int NS  = NSW + NSE;   // 640
static constexpr int NHD = 64;

DEV f32x4 mfma16(bf16x8 a, bf16x8 b, f32x4 c){
  return __builtin_amdgcn_mfma_f32_16x16x32_bf16(a, b, c, 0, 0, 0);
}

DEV void gload16(const bf16* g, bf16* l){
  __builtin_amdgcn_global_load_lds((const __attribute__((address_space(1))) void*)g,
                                   (__attribute__((address_space(3))) void*)l,
                                   16, 0, 0);
}

DEV bf16 tobf(float f){ return __float2bfloat16(f); }

union PK4 { bf16 h[4]; short4 s; };

// ---------- casts: fp32 -> bf16, plus build concatenated hidden ----------
__global__ __launch_bounds__(256) void cast_word_k(const float* __restrict__ wh,
                                                   bf16* __restrict__ whb,
                                                   bf16* __restrict__ hid){
  long i = ((long)blockIdx.x*256 + threadIdx.x)*4;
  float4 v = *reinterpret_cast<const float4*>(wh + i);
  PK4 p; p.h[0]=tobf(v.x); p.h[1]=tobf(v.y); p.h[2]=tobf(v.z); p.h[3]=tobf(v.w);
  *reinterpret_cast<short4*>(whb + i) = p.s;
  long row = i >> 10; int c = (int)(i & 1023);
  int b = (int)(row >> 9), s = (int)(row & 511);
  *reinterpret_cast<short4*>(hid + ((long)(b*NS + s) << 10) + c) = p.s;
}

__global__ __launch_bounds__(256) void cast_ent_k(const float* __restrict__ eh,
                                                  bf16* __restrict__ ehb,
                                                  bf16* __restrict__ hid){
  long i = ((long)blockIdx.x*256 + threadIdx.x)*4;
  float4 v = *reinterpret_cast<const float4*>(eh + i);
  PK4 p; p.h[0]=tobf(v.x); p.h[1]=tobf(v.y); p.h[2]=tobf(v.z); p.h[3]=tobf(v.w);
  *reinterpret_cast<short4*>(ehb + i) = p.s;
  long row = i >> 10; int c = (int)(i & 1023);
  int b = (int)(row >> 7), s = (int)(row & 127);
  *reinterpret_cast<short4*>(hid + ((long)(b*NS + NSW + s) << 10) + c) = p.s;
}

// ---------- batched 1024x1024 weight transpose+cast ----------
struct TP7 { const float* src[7]; bf16* dst[7]; };

__global__ void transpose7_k(TP7 tp){
  __shared__ float tile[32][33];
  const float* in = tp.src[blockIdx.z];
  bf16* out = tp.dst[blockIdx.z];
  const int c0 = blockIdx.x*32, r0 = blockIdx.y*32;
  const int tx = threadIdx.x, ty = threadIdx.y;
  #pragma unroll
  for (int i=0;i<4;i++)
    tile[ty + i*8][tx] = in[(long)(r0 + ty + i*8)*1024 + c0 + tx];
  __syncthreads();
  #pragma unroll
  for (int i=0;i<4;i++){
    int rr = ty + i*8;
    out[(long)(c0 + rr)*1024 + r0 + tx] = tobf(tile[tx][rr]);
  }
}

// generic (R,C) fp32 -> (C,R) bf16
__global__ void transpose_cast_k(const float* __restrict__ in, bf16* __restrict__ out,
                                 int R, int C){
  __shared__ float tile[32][33];
  const int c0 = blockIdx.x*32, r0 = blockIdx.y*32;
  const int tx = threadIdx.x, ty = threadIdx.y;
  #pragma unroll
  for (int i=0;i<4;i++)
    tile[ty + i*8][tx] = in[(long)(r0 + ty + i*8)*C + c0 + tx];
  __syncthreads();
  #pragma unroll
  for (int i=0;i<4;i++){
    int rr = ty + i*8;
    out[(long)(c0 + rr)*R + r0 + tx] = tobf(tile[tx][rr]);
  }
}

__global__ void bias_concat_k(const float* __restrict__ bq, const float* __restrict__ bw2e,
                              const float* __restrict__ be2w, const float* __restrict__ be2e,
                              const float* __restrict__ bk, const float* __restrict__ bv,
                              float* __restrict__ bQw, float* __restrict__ bQe,
                              float* __restrict__ bKV){
  int i = blockIdx.x*256 + threadIdx.x;
  bQw[i] = bq[i];   bQw[1024+i] = bw2e[i];
  bQe[i] = be2w[i]; bQe[1024+i] = be2e[i];
  bKV[i] = bk[i];   bKV[1024+i] = bv[i];
}

// ---------- GEMM: C(M,N) = A(M,K) @ Bt(N,K)^T + bias, bf16 MFMA ----------
// EPI: 0 = bf16 out (M,N); 3 = GELU(exact)->bf16 (M,N);
//      4 = fused KV: col<1024 -> bf16 (M,2048), col>=1024 -> Vt(B,H,64,NS);
//      5 = fp32 split-K partial: blockIdx.z selects K-half; z==0 -> Cout (+bias), z==1 -> Cout2
template<int EPI>
__global__ __launch_bounds__(256) void gemm_bt_k(const bf16* __restrict__ A,
                                                 const bf16* __restrict__ Bt,
                                                 const float* __restrict__ bias,
                                                 void* __restrict__ Cout,
                                                 void* __restrict__ Cout2,
                                                 int M, int N, int K){
  __shared__ __align__(16) bf16 As[128*64];
  __shared__ __align__(16) bf16 Bs[128*64];
  const int tid = threadIdx.x;

  // bijective XCD swizzle (m204)
  const int nwg = gridDim.x*gridDim.y;
  const int orig = blockIdx.y*gridDim.x + blockIdx.x;
  const int qq = nwg >> 3, rr8 = nwg & 7;
  const int xcd = orig & 7, idx = orig >> 3;
  const int wg = (xcd < rr8 ? xcd*(qq+1) : rr8*(qq+1) + (xcd-rr8)*qq) + idx;
  const int m0 = (wg / gridDim.x)*128, n0 = (wg % gridDim.x)*128;

  const int Kc  = K / gridDim.z;            // K-range per z-slice
  const int kt0 = blockIdx.z * Kc;

  const int wid = tid>>6, lane = tid&63;
  const int wr = wid>>1, wc = wid&1;
  const int lr = lane&15, lg = lane>>4;

  const f32x4 zero = {0.f,0.f,0.f,0.f};
  f32x4 acc[4][4];
  #pragma unroll
  for (int m=0;m<4;m++)
    #pragma unroll
    for (int n=0;n<4;n++) acc[m][n] = zero;

  for (int kt=kt0; kt<kt0+Kc; kt+=64){
    #pragma unroll
    for (int i=0;i<4;i++){
      int idx2 = i*256 + tid;
      int row = idx2>>3, kc = idx2&7;
      gload16(A + (long)(m0+row)*K + kt + kc*8, As + idx2*8);
    }
    #pragma unroll
    for (int i=0;i<4;i++){
      int idx2 = i*256 + tid;
      int row = idx2>>3, kc = idx2&7;
      gload16(Bt + (long)(n0+row)*K + kt + kc*8, Bs + idx2*8);
    }
    __syncthreads();
    #pragma unroll
    for (int ks=0; ks<2; ks++){
      bf16x8 af[4], bg[4];
      #pragma unroll
      for (int m=0;m<4;m++)
        af[m] = *reinterpret_cast<const bf16x8*>(As + (wr*64 + m*16 + lr)*64 + ks*32 + lg*8);
      #pragma unroll
      for (int n=0;n<4;n++)
        bg[n] = *reinterpret_cast<const bf16x8*>(Bs + (wc*64 + n*16 + lr)*64 + ks*32 + lg*8);
      __builtin_amdgcn_s_setprio(1);
      #pragma unroll
      for (int m=0;m<4;m++)
        #pragma unroll
        for (int n=0;n<4;n++)
          acc[m][n] = mfma16(af[m], bg[n], acc[m][n]);
      __builtin_amdgcn_s_setprio(0);
    }
    __syncthreads();
  }

  #pragma unroll
  for (int m=0;m<4;m++){
    const int rbase = m0 + wr*64 + m*16 + lg*4;
    #pragma unroll
    for (int n=0;n<4;n++){
      const int col = n0 + wc*64 + n*16 + lr;
      const float bsv = (EPI == 5 && blockIdx.z != 0) ? 0.f : bias[col];
      #pragma unroll
      for (int r=0;r<4;r++){
        const int rw = rbase + r;
        float v = acc[m][n][r] + bsv;
        if constexpr (EPI == 0){
          ((bf16*)Cout)[(long)rw*N + col] = tobf(v);
        } else if constexpr (EPI == 3){
          float ge = 0.5f*v*(1.0f + erff(v*0.70710678118654752f));
          ((bf16*)Cout)[(long)rw*N + col] = tobf(ge);
        } else if constexpr (EPI == 4){
          if (col < 1024){
            ((bf16*)Cout)[(long)rw*2048 + col] = tobf(v);
          } else {
            int bb = rw / NS, ss = rw % NS, hh = (col-1024) >> 6, dd = (col-1024) & 63;
            ((bf16*)Cout2)[((long)((bb*NH + hh)*NHD + dd))*NS + ss] = tobf(v);
          }
        } else {  // EPI == 5
          float* dst = blockIdx.z == 0 ? (float*)Cout : (float*)Cout2;
          dst[(long)rw*N + col] = v;
        }
      }
    }
  }
}

// ---------- fused entity-aware flash attention, split-K x4 ----------
// One block = one 32-query tile of one (b,h). Wave w scans key-tiles [5w,5w+5);
// partials (m,l,acc) merged through LDS at the end.
__global__ __launch_bounds__(256) void attn_k(
    const bf16* __restrict__ Qw,  // (B*SW,2048): [:,0:1024)=w2w, [:,1024:)=w2e
    const bf16* __restrict__ Qe,  // (B*SE,2048): [:,0:1024)=e2w, [:,1024:)=e2e
    const bf16* __restrict__ KV,  // (B*NS,2048): [:,0:1024)=K
    const bf16* __restrict__ Vt,  // (B,H,64,NS)
    const float* __restrict__ wm, const float* __restrict__ em,
    bf16* __restrict__ ctx){      // (B*NS,1024)
  __shared__ __align__(16) bf16 Plds[4][2][16*40];
  __shared__ float mred[4][2][16];
  __shared__ float lred[4][2][16];
  __shared__ __align__(16) float accred[4][16][64];
  const int tid = threadIdx.x, wid = tid>>6, lane = tid&63;
  const int lr = lane&15, lg = lane>>4;
  const int w   = blockIdx.x;
  const int b   = w / (NH*20);
  const int rem = w % (NH*20);
  const int h   = rem / 20;
  const int q0  = (rem % 20)*32;

  const bf16* Qbase; long qrow0;
  if (q0 < NSW){ Qbase = Qw; qrow0 = (long)b*NSW + q0; }
  else         { Qbase = Qe; qrow0 = (long)b*NSE + (q0 - NSW); }

  bf16x8 qA[2][2], qB[2][2];   // [m][dc]: A = "2w" half, B = "2e" half
  #pragma unroll
  for (int m=0;m<2;m++)
    #pragma unroll
    for (int dc=0; dc<2; dc++){
      long o = (qrow0 + m*16 + lr)*2048 + h*NHD + dc*32 + lg*8;
      qA[m][dc] = *reinterpret_cast<const bf16x8*>(Qbase + o);
      qB[m][dc] = *reinterpret_cast<const bf16x8*>(Qbase + o + 1024);
    }

  const f32x4 zero = {0.f,0.f,0.f,0.f};
  f32x4 cacc[2][4];
  float mrow[2][4], lsum[2][4];
  #pragma unroll
  for (int m=0;m<2;m++){
    #pragma unroll
    for (int dt=0;dt<4;dt++) cacc[m][dt] = zero;
    #pragma unroll
    for (int r=0;r<4;r++){ mrow[m][r] = -1e30f; lsum[m][r] = 0.f; }
  }

  const bf16* Kbase = KV + (long)b*NS*2048 + h*NHD;
  const bf16* Vbase = Vt + (long)((b*NH + h)*NHD)*NS;

  for (int kt=wid*5; kt<wid*5+5; kt++){
    const int k0 = kt*32;
    const bool word = (k0 < NSW);

    bf16x8 kf[2][2], vf[4];
    #pragma unroll
    for (int sub=0;sub<2;sub++)
      #pragma unroll
      for (int dc=0;dc<2;dc++)
        kf[sub][dc] = *reinterpret_cast<const bf16x8*>(
            Kbase + (long)(k0 + sub*16 + lr)*2048 + dc*32 + lg*8);
    #pragma unroll
    for (int dt=0;dt<4;dt++)
      vf[dt] = *reinterpret_cast<const bf16x8*>(
          Vbase + (long)(dt*16 + lr)*NS + k0 + lg*8);

    float msk0, msk1;
    { int k = k0 + lr;
      msk0 = word ? wm[b*NSW + k]      : em[b*NSE + (k - NSW)];
      msk1 = word ? wm[b*NSW + k + 16] : em[b*NSE + (k + 16 - NSW)];
    }

    f32x4 sc[2][2];
    #pragma unroll
    for (int m=0;m<2;m++){ sc[m][0]=zero; sc[m][1]=zero; }
    __builtin_amdgcn_s_setprio(1);
    #pragma unroll
    for (int m=0;m<2;m++)
      #pragma unroll
      for (int sub=0;sub<2;sub++)
        #pragma unroll
        for (int dc=0;dc<2;dc++){
          const bf16x8 q = word ? qA[m][dc] : qB[m][dc];
          sc[m][sub] = mfma16(q, kf[sub][dc], sc[m][sub]);
        }
    __builtin_amdgcn_s_setprio(0);

    #pragma unroll
    for (int m=0;m<2;m++){
      bf16* pw = &Plds[wid][m][0];
      #pragma unroll
      for (int r=0;r<4;r++){
        float s0 = sc[m][0][r]*0.125f + msk0;
        float s1 = sc[m][1][r]*0.125f + msk1;
        float t = fmaxf(s0, s1);
        #pragma unroll
        for (int o=8;o;o>>=1) t = fmaxf(t, __shfl_xor(t, o, 16));
        float mn = fmaxf(mrow[m][r], t);
        float al = __expf(mrow[m][r] - mn);
        mrow[m][r] = mn;
        float p0 = __expf(s0 - mn), p1 = __expf(s1 - mn);
        float ps = p0 + p1;
        #pragma unroll
        for (int o=8;o;o>>=1) ps += __shfl_xor(ps, o, 16);
        lsum[m][r] = lsum[m][r]*al + ps;
        pw[(lg*4+r)*40 + lr]      = tobf(p0);
        pw[(lg*4+r)*40 + 16 + lr] = tobf(p1);
        #pragma unroll
        for (int dt=0;dt<4;dt++) cacc[m][dt][r] *= al;
      }
    }

    __builtin_amdgcn_s_setprio(1);
    #pragma unroll
    for (int m=0;m<2;m++){
      bf16x8 pa = *reinterpret_cast<const bf16x8*>(&Plds[wid][m][0] + lr*40 + lg*8);
      #pragma unroll
      for (int dt=0;dt<4;dt++)
        cacc[m][dt] = mfma16(pa, vf[dt], cacc[m][dt]);
    }
    __builtin_amdgcn_s_setprio(0);
  }

  // ---- merge the 4 per-wave partials ----
  #pragma unroll
  for (int m=0;m<2;m++)
    #pragma unroll
    for (int r=0;r<4;r++)
      if (lr == 0){
        mred[wid][m][lg*4+r] = mrow[m][r];
        lred[wid][m][lg*4+r] = lsum[m][r];
      }
  __syncthreads();

  float Lg[2][4], scl[2][4];
  #pragma unroll
  for (int m=0;m<2;m++)
    #pragma unroll
    for (int r=0;r<4;r++){
      const int row = lg*4 + r;
      float M0 = fmaxf(fmaxf(mred[0][m][row], mred[1][m][row]),
                       fmaxf(mred[2][m][row], mred[3][m][row]));
      float lt = 0.f;
      #pragma unroll
      for (int ww=0; ww<4; ww++)
        lt += lred[ww][m][row] * __expf(mred[ww][m][row] - M0);
      Lg[m][r]  = lt;
      scl[m][r] = __expf(mrow[m][r] - M0);
    }

  const long crow = (long)b*NS + q0;
  #pragma unroll
  for (int m=0;m<2;m++){
    #pragma unroll
    for (int dt=0;dt<4;dt++)
      #pragma unroll
      for (int r=0;r<4;r++)
        accred[wid][dt*4+r][lane] = cacc[m][dt][r] * scl[m][r];
    __syncthreads();
    { const int dt = wid;
      #pragma unroll
      for (int r=0;r<4;r++){
        float s = accred[0][dt*4+r][lane] + accred[1][dt*4+r][lane]
                + accred[2][dt*4+r][lane] + accred[3][dt*4+r][lane];
        s /= Lg[m][r];
        ctx[(crow + m*16 + lg*4 + r)*ND + h*NHD + dt*16 + lr] = tobf(s);
      }
    }
    __syncthreads();
  }
}

// ---------- LayerNorm kernels (fp32, fused residual + split-K partial add) ----------
DEV void block_red2(float& s1, float& s2){
  __shared__ float red[8];
  #pragma unroll
  for (int o=32;o;o>>=1){ s1 += __shfl_down(s1,o); s2 += __shfl_down(s2,o); }
  int wid = threadIdx.x>>6, lane = threadIdx.x&63;
  if (lane==0){ red[wid]=s1; red[4+wid]=s2; }
  __syncthreads();
  s1 = red[0]+red[1]+red[2]+red[3];
  s2 = red[4]+red[5]+red[6]+red[7];
}

__global__ __launch_bounds__(256) void ln1_k(const float* __restrict__ ctxO,
    const float* __restrict__ ctxO1,
    const float* __restrict__ wh, const float* __restrict__ eh,
    const float* __restrict__ g, const float* __restrict__ be,
    float* __restrict__ outF, bf16* __restrict__ outB){
  const int row = blockIdx.x;
  const int b = row / NS, s = row % NS;
  const float* resid = (s < NSW) ? wh + ((long)(b*NSW + s))*ND
                                 : eh + ((long)(b*NSE + (s-NSW)))*ND;
  const int t = threadIdx.x;
  float4 xv = reinterpret_cast<const float4*>(ctxO + (long)row*ND)[t];
  float4 x1 = reinterpret_cast<const float4*>(ctxO1 + (long)row*ND)[t];
  float4 rv = reinterpret_cast<const float4*>(resid)[t];
  float4 x = make_float4(xv.x+x1.x+rv.x, xv.y+x1.y+rv.y, xv.z+x1.z+rv.z, xv.w+x1.w+rv.w);
  float s1 = x.x+x.y+x.z+x.w;
  float s2 = x.x*x.x + x.y*x.y + x.z*x.z + x.w*x.w;
  block_red2(s1, s2);
  float mean = s1 * (1.f/ND);
  float var  = s2 * (1.f/ND) - mean*mean;
  float rstd = rsqrtf(var + 1e-12f);
  float4 gv = reinterpret_cast<const float4*>(g)[t];
  float4 bv = reinterpret_cast<const float4*>(be)[t];
  float4 y = make_float4(gv.x*(x.x-mean)*rstd + bv.x,
                         gv.y*(x.y-mean)*rstd + bv.y,
                         gv.z*(x.z-mean)*rstd + bv.z,
                         gv.w*(x.w-mean)*rstd + bv.w);
  reinterpret_cast<float4*>(outF + (long)row*ND)[t] = y;
  PK4 p; p.h[0]=tobf(y.x); p.h[1]=tobf(y.y); p.h[2]=tobf(y.z); p.h[3]=tobf(y.w);
  reinterpret_cast<short4*>(outB + (long)row*ND)[t] = p.s;
}

__global__ __launch_bounds__(256) void ln2_k(const float* __restrict__ ffo,
    const float* __restrict__ ffo1,
    const float* __restrict__ attnF, const float* __restrict__ g,
    const float* __restrict__ be, float* __restrict__ out){
  const int row = blockIdx.x;
  const int b = row / NS, s = row % NS;
  const int t = threadIdx.x;
  float4 xv = reinterpret_cast<const float4*>(ffo + (long)row*ND)[t];
  float4 x1 = reinterpret_cast<const float4*>(ffo1 + (long)row*ND)[t];
  float4 rv = reinterpret_cast<const float4*>(attnF + (long)row*ND)[t];
  float4 x = make_float4(xv.x+x1.x+rv.x, xv.y+x1.y+rv.y, xv.z+x1.z+rv.z, xv.w+x1.w+rv.w);
  float s1 = x.x+x.y+x.z+x.w;
  float s2 = x.x*x.x + x.y*x.y + x.z*x.z + x.w*x.w;
  block_red2(s1, s2);
  float mean = s1 * (1.f/ND);
  float var  = s2 * (1.f/ND) - mean*mean;
  float rstd = rsqrtf(var + 1e-12f);
  float4 gv = reinterpret_cast<const float4*>(g)[t];
  float4 bv = reinterpret_cast<const float4*>(be)[t];
  float4 y = make_float4(gv.x*(x.x-mean)*rstd + bv.x,
                         gv.y*(x.y-mean)*rstd + bv.y,
                         gv.z*(x.z-mean)*rstd + bv.z,
                         gv.w*(x.w-mean)*rstd + bv.w);
  float* op = (s < NSW) ? out + ((long)(b*NSW+s))*ND
                        : out + (long)NB*NSW*ND + ((long)(b*NSE + (s-NSW)))*ND;
  reinterpret_cast<float4*>(op)[t] = y;
}

// ---------- host ----------
extern "C" void kernel_launch(void* const* d_in, const int* in_sizes, int n_in,
                              void* d_out, int out_size, void* d_ws, size_t ws_size,
                              hipStream_t stream){
  (void)in_sizes; (void)n_in; (void)out_size; (void)ws_size;
  const float* wh   = (const float*)d_in[0];
  const float* eh   = (const float*)d_in[1];
  const float* wm   = (const float*)d_in[2];
  const float* em   = (const float*)d_in[3];
  const float* Wq   = (const float*)d_in[4];   const float* bq   = (const float*)d_in[5];
  const float* Ww2e = (const float*)d_in[6];   const float* bw2e = (const float*)d_in[7];
  const float* We2w = (const float*)d_in[8];   const float* be2w = (const float*)d_in[9];
  const float* We2e = (const float*)d_in[10];  const float* be2e = (const float*)d_in[11];
  const float* Wk   = (const float*)d_in[12];  const float* bk   = (const float*)d_in[13];
  const float* Wv   = (const float*)d_in[14];  const float* bv   = (const float*)d_in[15];
  const float* Wo   = (const float*)d_in[16];  const float* bo   = (const float*)d_in[17];
  const float* g1   = (const float*)d_in[18];  const float* b1   = (const float*)d_in[19];
  const float* Wi   = (const float*)d_in[20];  const float* bi   = (const float*)d_in[21];
  const float* Wout = (const float*)d_in[22];  const float* bout = (const float*)d_in[23];
  const float* g2   = (const float*)d_in[24];  const float* b2   = (const float*)d_in[25];
  float* out = (float*)d_out;

  char* ws = (char*)d_ws;
  size_t off = 0;
  auto alloc = [&](size_t bytes)->char*{
    char* p = ws + off; off += (bytes + 255) & ~(size_t)255; return p;
  };

  // NOTE: hid+whb+ehb are contiguous 20 MB; dead after the KV GEMM, reused as
  // the split-K partial-1 buffer (5120x1024 fp32 = 20 MB) for Wo and FFN2.
  bf16* hid   = (bf16*)alloc((size_t)NB*NS*ND*2);     // 10 MB
  bf16* whb   = (bf16*)alloc((size_t)NB*NSW*ND*2);    //  8 MB
  bf16* ehb   = (bf16*)alloc((size_t)NB*NSE*ND*2);    //  2 MB
  float* part1 = (float*)hid;
  bf16* WqwT  = (bf16*)alloc((size_t)2048*ND*2);   // [Wq^T ; Ww2e^T]
  bf16* WqeT  = (bf16*)alloc((size_t)2048*ND*2);   // [We2w^T ; We2e^T]
  bf16* WkvT  = (bf16*)alloc((size_t)2048*ND*2);   // [Wk^T ; Wv^T]
  bf16* WoT   = (bf16*)alloc((size_t)ND*ND*2);
  bf16* WiT   = (bf16*)alloc((size_t)NFF*ND*2);
  bf16* WoutT = (bf16*)alloc((size_t)ND*NFF*2);
  float* bQw  = (float*)alloc(2048*4);
  float* bQe  = (float*)alloc(2048*4);
  float* bKV  = (float*)alloc(2048*4);

  // union region: {Qw, Qe, KV, Vt} reused as {inter, attnB} after attention
  char* u1 = alloc((size_t)52428800);
  bf16* Qwb = (bf16*)u1;                               // (B*SW, 2048) = 16 MB
  bf16* Qeb = Qwb + (size_t)NB*NSW*2048;               // (B*SE, 2048) = 4 MB
  bf16* KVb = Qeb + (size_t)NB*NSE*2048;               // (B*NS, 2048) = 20 MB
  bf16* Vt  = KVb + (size_t)NB*NS*2048;                // (B,H,64,NS) = 10 MB
  bf16* inter = (bf16*)u1;                             // (B*NS, 4096) = 40 MB
  bf16* attnB = (bf16*)(u1 + (size_t)41943040);        // (B*NS, 1024) = 10 MB (over Vt)

  bf16*  ctx   = (bf16*)alloc((size_t)NB*NS*ND*2);
  float* ctxO  = (float*)alloc((size_t)NB*NS*ND*4);    // reused as ffo
  float* ffo   = ctxO;
  float* attnF = (float*)alloc((size_t)NB*NS*ND*4);

  dim3 tb(32,8);
  cast_word_k<<<4096, 256, 0, stream>>>(wh, whb, hid);
  cast_ent_k <<<1024, 256, 0, stream>>>(eh, ehb, hid);

  TP7 tp;
  tp.src[0]=Wq;   tp.dst[0]=WqwT;
  tp.src[1]=Ww2e; tp.dst[1]=WqwT + (size_t)1024*1024;
  tp.src[2]=We2w; tp.dst[2]=WqeT;
  tp.src[3]=We2e; tp.dst[3]=WqeT + (size_t)1024*1024;
  tp.src[4]=Wk;   tp.dst[4]=WkvT;
  tp.src[5]=Wv;   tp.dst[5]=WkvT + (size_t)1024*1024;
  tp.src[6]=Wo;   tp.dst[6]=WoT;
  transpose7_k<<<dim3(32,32,7), tb, 0, stream>>>(tp);
  transpose_cast_k<<<dim3(128,32), tb, 0, stream>>>(Wi,   WiT,   ND, NFF);
  transpose_cast_k<<<dim3(32,128), tb, 0, stream>>>(Wout, WoutT, NFF, ND);
  bias_concat_k<<<4, 256, 0, stream>>>(bq, bw2e, be2w, be2e, bk, bv, bQw, bQe, bKV);

  gemm_bt_k<0><<<dim3(16,32), 256, 0, stream>>>(whb, WqwT, bQw, Qwb, nullptr, NB*NSW, 2048, ND);
  gemm_bt_k<0><<<dim3(16, 8), 256, 0, stream>>>(ehb, WqeT, bQe, Qeb, nullptr, NB*NSE, 2048, ND);
  gemm_bt_k<4><<<dim3(16,40), 256, 0, stream>>>(hid, WkvT, bKV, KVb, Vt,      NB*NS,  2048, ND);

  attn_k<<<2560, 256, 0, stream>>>(Qwb, Qeb, KVb, Vt, wm, em, ctx);

  gemm_bt_k<5><<<dim3(8,40,2),  256, 0, stream>>>(ctx,   WoT,   bo,   ctxO, part1, NB*NS, ND,  ND);
  ln1_k<<<5120, 256, 0, stream>>>(ctxO, part1, wh, eh, g1, b1, attnF, attnB);
  gemm_bt_k<3><<<dim3(32,40),   256, 0, stream>>>(attnB, WiT,   bi,   inter, nullptr, NB*NS, NFF, ND);
  gemm_bt_k<5><<<dim3(8,40,2),  256, 0, stream>>>(inter, WoutT, bout, ffo,  part1, NB*NS, ND,  NFF);
  ln2_k<<<5120, 256, 0, stream>>>(ffo, part1, attnF, g2, b2, out);
}